// Round 1
// baseline (328.505 us; speedup 1.0000x reference)
//
#include <hip/hip_runtime.h>
#include <hip/hip_bf16.h>
#include <math.h>

#define B_ 8
#define T_ 2048
#define C_ 1024
#define H_ 128
#define M_ (B_*T_)   // 16384

typedef __attribute__((ext_vector_type(8))) short bf16x8;
typedef __attribute__((ext_vector_type(8))) unsigned short u16x8;
typedef __attribute__((ext_vector_type(4))) float f32x4;

#define MFMA(a,b,c) __builtin_amdgcn_mfma_f32_16x16x32_bf16((a),(b),(c),0,0,0)

__device__ __forceinline__ unsigned short f2bf(float f) {
    union { float f; unsigned u; } v; v.f = f;
    unsigned r = v.u + 0x7fffu + ((v.u >> 16) & 1u);
    return (unsigned short)(r >> 16);
}

// ---------------- kernel 1: W fp32 -> bf16, concat [Wq;Wk;Wv] = [384][1024] ----
__global__ __launch_bounds__(256) void wconv(const float* __restrict__ Wq,
                                             const float* __restrict__ Wk,
                                             const float* __restrict__ Wv,
                                             unsigned short* __restrict__ Wb) {
    int i = blockIdx.x * 256 + threadIdx.x;          // 0..393215
    const int N1 = H_ * C_;                          // 131072
    const float* src = (i < N1) ? Wq : (i < 2 * N1 ? Wk : Wv);
    int j = i & (N1 - 1);
    Wb[i] = f2bf(src[j]);
}

// ---------------- kernel 2: fused QKV projection --------------------------------
// Y[m][n] = sum_k X[m][k] * W[n][k];  m-tile 64, n = 384 (q|k|v), K=1024
__global__ __launch_bounds__(256) void proj(const float* __restrict__ x,
                                            const unsigned short* __restrict__ Wb,
                                            unsigned short* __restrict__ Q,
                                            unsigned short* __restrict__ K,
                                            unsigned short* __restrict__ V) {
    __shared__ unsigned short Xs[64][32];    // 4 KB
    __shared__ unsigned short Ws[384][32];   // 24 KB

    const int tid  = threadIdx.x;
    const int wave = tid >> 6, lane = tid & 63;
    const int quad = lane >> 4, l16 = lane & 15;
    const int m0   = blockIdx.x * 64;

    f32x4 acc[24];
    for (int i = 0; i < 24; i++) acc[i] = {0.f, 0.f, 0.f, 0.f};

    const int xr  = tid >> 2;          // 0..63
    const int xkb = (tid & 3) * 8;     // 0,8,16,24

    for (int kc = 0; kc < C_; kc += 32) {
        // stage X tile (fp32 -> bf16)
        const float* xp = x + (size_t)(m0 + xr) * C_ + kc + xkb;
        float4 a0 = *(const float4*)xp;
        float4 a1 = *(const float4*)(xp + 4);
        u16x8 xv;
        xv[0] = f2bf(a0.x); xv[1] = f2bf(a0.y); xv[2] = f2bf(a0.z); xv[3] = f2bf(a0.w);
        xv[4] = f2bf(a1.x); xv[5] = f2bf(a1.y); xv[6] = f2bf(a1.z); xv[7] = f2bf(a1.w);
        *(u16x8*)&Xs[xr][xkb] = xv;
        // stage W tile (bf16 passthrough): 384*32 elems = 1536 groups of 8
        #pragma unroll
        for (int i = 0; i < 6; i++) {
            int g = tid + 256 * i;
            int wr = g >> 2, wkb = (g & 3) * 8;
            *(u16x8*)&Ws[wr][wkb] = *(const u16x8*)(Wb + (size_t)wr * C_ + kc + wkb);
        }
        __syncthreads();

        bf16x8 afrag = *(bf16x8*)&Xs[wave * 16 + l16][quad * 8];
        #pragma unroll
        for (int n = 0; n < 24; n++) {
            bf16x8 bfrag = *(bf16x8*)&Ws[n * 16 + l16][quad * 8];
            acc[n] = MFMA(afrag, bfrag, acc[n]);
        }
        __syncthreads();
    }

    // epilogue: row = m0 + wave*16 + quad*4 + r ; gcol = n*16 + l16
    #pragma unroll
    for (int n = 0; n < 24; n++) {
        int gcol  = n * 16 + l16;
        int which = gcol >> 7;           // uniform per frag
        int c     = gcol & 127;
        unsigned short* dst = (which == 0) ? Q : (which == 1 ? K : V);
        #pragma unroll
        for (int r = 0; r < 4; r++) {
            int row = m0 + wave * 16 + quad * 4 + r;
            dst[(size_t)row * H_ + c] = f2bf(acc[n][r]);
        }
    }
}

// ---------------- kernel 3: flash causal attention ------------------------------
// grid (32, 8): qt, b.  Q-tile 64 rows (wave handles 16), K/V tiles of 32.
__global__ __launch_bounds__(256) void attn(const unsigned short* __restrict__ Qg,
                                            const unsigned short* __restrict__ Kg,
                                            const unsigned short* __restrict__ Vg,
                                            float* __restrict__ out) {
    __shared__ unsigned short Qs[64][128];     // 16 KB
    __shared__ unsigned short Ks[32][128];     //  8 KB
    __shared__ unsigned short Vt[128][32];     //  8 KB (transposed: [n][k])
    __shared__ unsigned short Ps[4][16][32];   //  4 KB (per-wave P in A-layout)

    const int tid  = threadIdx.x;
    const int wave = tid >> 6, lane = tid & 63;
    const int quad = lane >> 4, l16 = lane & 15;
    const int b = blockIdx.y, qt = blockIdx.x;
    const int qbase = qt * 64;
    const size_t base = (size_t)b * T_ * H_;

    // load Q tile: 8192 bf16, 4 groups of 8 per thread
    #pragma unroll
    for (int i = 0; i < 4; i++) {
        int g = tid + 256 * i;
        int r = g >> 4, kb = (g & 15) * 8;
        *(u16x8*)&Qs[r][kb] = *(const u16x8*)(Qg + base + (size_t)(qbase + r) * H_ + kb);
    }
    __syncthreads();

    // loop-invariant Q A-frags (16 rows x 128 K, 4 frags of K=32)
    bf16x8 qfrag[4];
    #pragma unroll
    for (int kk = 0; kk < 4; kk++)
        qfrag[kk] = *(bf16x8*)&Qs[wave * 16 + l16][kk * 32 + quad * 8];

    f32x4 o[8];
    #pragma unroll
    for (int i = 0; i < 8; i++) o[i] = {0.f, 0.f, 0.f, 0.f};
    float m_i[4], l_i[4];
    #pragma unroll
    for (int r = 0; r < 4; r++) { m_i[r] = -INFINITY; l_i[r] = 0.f; }

    const float sc = 0.08838834764831845f;   // 1/sqrt(128)
    const int nkt = (qbase + 63) / 32 + 1;   // causal bound

    for (int kt = 0; kt < nkt; kt++) {
        const int kbase = kt * 32;
        // stage K tile (natural [t][h])
        #pragma unroll
        for (int i = 0; i < 2; i++) {
            int g = tid + 256 * i;
            int r = g >> 4, kb = (g & 15) * 8;
            *(u16x8*)&Ks[r][kb] = *(const u16x8*)(Kg + base + (size_t)(kbase + r) * H_ + kb);
        }
        // stage V tile transposed -> Vt[n][k]
        #pragma unroll
        for (int i = 0; i < 2; i++) {
            int g = tid + 256 * i;
            int r = g >> 4, nb = (g & 15) * 8;
            u16x8 v = *(const u16x8*)(Vg + base + (size_t)(kbase + r) * H_ + nb);
            #pragma unroll
            for (int j = 0; j < 8; j++) Vt[nb + j][r] = v[j];
        }
        __syncthreads();

        // S = Q K^T : 16 rows x 32 cols per wave
        f32x4 s0 = {0.f, 0.f, 0.f, 0.f}, s1 = {0.f, 0.f, 0.f, 0.f};
        #pragma unroll
        for (int kk = 0; kk < 4; kk++) {
            bf16x8 b0 = *(bf16x8*)&Ks[l16][kk * 32 + quad * 8];
            bf16x8 b1 = *(bf16x8*)&Ks[16 + l16][kk * 32 + quad * 8];
            s0 = MFMA(qfrag[kk], b0, s0);
            s1 = MFMA(qfrag[kk], b1, s1);
        }

        // scale + causal mask + online softmax
        float p0[4], p1[4], rowmax[4];
        const int qrow = qbase + wave * 16 + quad * 4;
        const int kg0 = kbase + l16, kg1 = kbase + 16 + l16;
        #pragma unroll
        for (int r = 0; r < 4; r++) {
            float v0 = s0[r] * sc, v1 = s1[r] * sc;
            int qg = qrow + r;
            if (kg0 > qg) v0 = -INFINITY;
            if (kg1 > qg) v1 = -INFINITY;
            p0[r] = v0; p1[r] = v1;
            rowmax[r] = fmaxf(v0, v1);
        }
        #pragma unroll
        for (int r = 0; r < 4; r++) {
            float v = rowmax[r];
            v = fmaxf(v, __shfl_xor(v, 1, 64));
            v = fmaxf(v, __shfl_xor(v, 2, 64));
            v = fmaxf(v, __shfl_xor(v, 4, 64));
            v = fmaxf(v, __shfl_xor(v, 8, 64));
            rowmax[r] = v;
        }
        float alpha[4], rowsum[4];
        #pragma unroll
        for (int r = 0; r < 4; r++) {
            float mnew = fmaxf(m_i[r], rowmax[r]);
            alpha[r] = __expf(m_i[r] - mnew);
            m_i[r] = mnew;
            float e0 = __expf(p0[r] - mnew);
            float e1 = __expf(p1[r] - mnew);
            p0[r] = e0; p1[r] = e1;
            rowsum[r] = e0 + e1;
        }
        #pragma unroll
        for (int r = 0; r < 4; r++) {
            float v = rowsum[r];
            v += __shfl_xor(v, 1, 64);
            v += __shfl_xor(v, 2, 64);
            v += __shfl_xor(v, 4, 64);
            v += __shfl_xor(v, 8, 64);
            l_i[r] = alpha[r] * l_i[r] + v;
        }
        // rescale O
        #pragma unroll
        for (int i = 0; i < 8; i++)
            #pragma unroll
            for (int r = 0; r < 4; r++) o[i][r] *= alpha[r];

        // write P (C-layout) -> Ps (A-layout source), per-wave region
        #pragma unroll
        for (int r = 0; r < 4; r++) {
            Ps[wave][quad * 4 + r][l16]      = f2bf(p0[r]);
            Ps[wave][quad * 4 + r][16 + l16] = f2bf(p1[r]);
        }
        // P·V  (A from Ps, B from Vt)
        bf16x8 pa = *(bf16x8*)&Ps[wave][l16][quad * 8];
        #pragma unroll
        for (int n = 0; n < 8; n++) {
            bf16x8 vb = *(bf16x8*)&Vt[n * 16 + l16][quad * 8];
            o[n] = MFMA(pa, vb, o[n]);
        }
        __syncthreads();
    }

    // epilogue: out = O / l
    #pragma unroll
    for (int n = 0; n < 8; n++) {
        int col = n * 16 + l16;
        #pragma unroll
        for (int r = 0; r < 4; r++) {
            int row = qbase + wave * 16 + quad * 4 + r;
            out[base + (size_t)row * H_ + col] = o[n][r] / l_i[r];
        }
    }
}

extern "C" void kernel_launch(void* const* d_in, const int* in_sizes, int n_in,
                              void* d_out, int out_size, void* d_ws, size_t ws_size,
                              hipStream_t stream) {
    const float* x  = (const float*)d_in[0];
    const float* Wq = (const float*)d_in[1];
    const float* Wk = (const float*)d_in[2];
    const float* Wv = (const float*)d_in[3];

    unsigned short* Wb = (unsigned short*)d_ws;                       // 768 KB
    unsigned short* Q  = (unsigned short*)((char*)d_ws + (1u << 20)); // 4 MB
    unsigned short* K  = Q + (size_t)M_ * H_;
    unsigned short* V  = K + (size_t)M_ * H_;
    float* out = (float*)d_out;

    hipLaunchKernelGGL(wconv, dim3(1536), dim3(256), 0, stream, Wq, Wk, Wv, Wb);
    hipLaunchKernelGGL(proj,  dim3(256),  dim3(256), 0, stream, x, Wb, Q, K, V);
    hipLaunchKernelGGL(attn,  dim3(32, 8), dim3(256), 0, stream, Q, K, V, out);
}

// Round 2
// 182.685 us; speedup vs baseline: 1.7982x; 1.7982x over previous
//
#include <hip/hip_runtime.h>
#include <math.h>

#define T_ 2048
#define C_ 1024
#define H_ 128
#define NB 8
#define XN 16777216   // 16384*1024 x elements
#define WN 131072     // 128*1024 per weight
#define SC 0.08838834764831845f   // 1/sqrt(128)

typedef __attribute__((ext_vector_type(8))) short bf16x8;
typedef __attribute__((ext_vector_type(8))) unsigned short u16x8;
typedef __attribute__((ext_vector_type(4))) float f32x4;

#define MFMA16(a,b,c) __builtin_amdgcn_mfma_f32_16x16x32_bf16((a),(b),(c),0,0,0)

__device__ __forceinline__ unsigned short f2bf(float f) {
    union { float f; unsigned u; } v; v.f = f;
    unsigned r = v.u + 0x7fffu + ((v.u >> 16) & 1u);
    return (unsigned short)(r >> 16);
}
__device__ __forceinline__ float bf2f(unsigned short u) {
    union { unsigned u; float f; } v; v.u = ((unsigned)u) << 16; return v.f;
}
// async global->LDS, 16B per lane; lds dest = uniform base + laneid*16
__device__ __forceinline__ void gld16(void* lds, const void* g) {
    __builtin_amdgcn_global_load_lds(
        (const __attribute__((address_space(1))) unsigned*)g,
        (__attribute__((address_space(3))) unsigned*)lds, 16, 0, 0);
}

// ---------- kernel 1: x and W fp32->bf16 (Wq pre-scaled by 1/sqrt(H)) ----------
__global__ __launch_bounds__(256) void xwconv(const float* __restrict__ x,
                                              const float* __restrict__ Wq,
                                              const float* __restrict__ Wk,
                                              const float* __restrict__ Wv,
                                              unsigned short* __restrict__ xb,
                                              unsigned short* __restrict__ Wb) {
    long e = ((long)blockIdx.x * 256 + threadIdx.x) * 8;
    u16x8 o;
    if (e < XN) {
        const float4* p = (const float4*)(x + e);
        float4 a = p[0], b = p[1];
        o[0]=f2bf(a.x); o[1]=f2bf(a.y); o[2]=f2bf(a.z); o[3]=f2bf(a.w);
        o[4]=f2bf(b.x); o[5]=f2bf(b.y); o[6]=f2bf(b.z); o[7]=f2bf(b.w);
        *(u16x8*)(xb + e) = o;
    } else {
        long j = e - XN;
        int which = (int)(j >> 17);
        long off = j & (WN - 1);
        const float* src = (which == 0) ? Wq : (which == 1 ? Wk : Wv);
        float s = (which == 0) ? SC : 1.0f;
        const float4* p = (const float4*)(src + off);
        float4 a = p[0], b = p[1];
        o[0]=f2bf(a.x*s); o[1]=f2bf(a.y*s); o[2]=f2bf(a.z*s); o[3]=f2bf(a.w*s);
        o[4]=f2bf(b.x*s); o[5]=f2bf(b.y*s); o[6]=f2bf(b.z*s); o[7]=f2bf(b.w*s);
        *(u16x8*)(Wb + j) = o;
    }
}

// ---------- kernel 2: QKV projection, m97-style 128x128 tiles, BK=32 ----------
// grid (128 m-tiles, 3 n-tiles): n-tile 0->Q, 1->K, 2->V
__global__ __launch_bounds__(256) void proj(const unsigned short* __restrict__ xb,
                                            const unsigned short* __restrict__ Wb,
                                            unsigned short* __restrict__ Q,
                                            unsigned short* __restrict__ K,
                                            unsigned short* __restrict__ V) {
    __shared__ unsigned short Xs[128][32];
    __shared__ unsigned short Ws[128][32];
    const int tid = threadIdx.x, wave = tid >> 6, lane = tid & 63;
    const int quad = lane >> 4, l16 = lane & 15;
    const int m0 = blockIdx.x * 128, n0 = blockIdx.y;
    const int wm = wave >> 1, wn = wave & 1;

    f32x4 acc[4][4];
    #pragma unroll
    for (int i = 0; i < 4; i++)
        #pragma unroll
        for (int j = 0; j < 4; j++) acc[i][j] = {0.f, 0.f, 0.f, 0.f};

    const unsigned short* xg = xb + (size_t)(m0 + wave * 32 + (lane >> 2)) * C_ + (lane & 3) * 8;
    const unsigned short* wg = Wb + (size_t)(n0 * 128 + wave * 32 + (lane >> 2)) * C_ + (lane & 3) * 8;

    for (int kc = 0; kc < C_; kc += 32) {
        gld16(&Xs[wave * 32][0],      xg + kc);
        gld16(&Xs[wave * 32 + 16][0], xg + kc + 16 * C_);
        gld16(&Ws[wave * 32][0],      wg + kc);
        gld16(&Ws[wave * 32 + 16][0], wg + kc + 16 * C_);
        __syncthreads();
        bf16x8 af[4], bfr[4];
        #pragma unroll
        for (int mf = 0; mf < 4; mf++) af[mf]  = *(bf16x8*)&Xs[wm * 64 + mf * 16 + l16][quad * 8];
        #pragma unroll
        for (int nf = 0; nf < 4; nf++) bfr[nf] = *(bf16x8*)&Ws[wn * 64 + nf * 16 + l16][quad * 8];
        #pragma unroll
        for (int mf = 0; mf < 4; mf++)
            #pragma unroll
            for (int nf = 0; nf < 4; nf++)
                acc[mf][nf] = MFMA16(af[mf], bfr[nf], acc[mf][nf]);
        __syncthreads();
    }

    unsigned short* dst = (n0 == 0) ? Q : (n0 == 1 ? K : V);
    #pragma unroll
    for (int mf = 0; mf < 4; mf++)
        #pragma unroll
        for (int nf = 0; nf < 4; nf++)
            #pragma unroll
            for (int r = 0; r < 4; r++)
                dst[(size_t)(m0 + wm * 64 + mf * 16 + quad * 4 + r) * H_ + wn * 64 + nf * 16 + l16]
                    = f2bf(acc[mf][nf][r]);
}

// ---------- kernel 3: split-K flash causal attention ----------
// grid (32 q-tiles, 8 batch, 4 splits of 512 K-rows); K-tile 64.
__global__ __launch_bounds__(256) void attn(const unsigned short* __restrict__ Qg,
                                            const unsigned short* __restrict__ Kg,
                                            const unsigned short* __restrict__ Vg,
                                            unsigned short* __restrict__ Ob,
                                            float* __restrict__ Ml) {
    const int qt = blockIdx.x, b = blockIdx.y, s = blockIdx.z;
    const int qbase = qt * 64, kstart = s * 512;
    if (kstart >= qbase + 64) return;               // inactive split
    const int kend  = (kstart + 512 < qbase + 64) ? kstart + 512 : qbase + 64;
    const int niter = (kend - kstart) >> 6;

    __shared__ unsigned short Qs[4][64][32];   // 16 KB, chunked by k
    __shared__ unsigned short Ks[4][64][32];   // 16 KB
    __shared__ unsigned short Vt[128 * 64];    // 16 KB, XOR-swizzled transpose
    __shared__ unsigned short Ps[4][16][72];   //  9 KB, per-wave P, padded

    const int tid = threadIdx.x, wave = tid >> 6, lane = tid & 63;
    const int quad = lane >> 4, l16 = lane & 15;
    const size_t base = (size_t)b * T_ * H_;

    // Q/K staging pointers: wave handles k-chunk = wave; instr p covers 16 rows x 32 cols
    const unsigned short* qsrc = Qg + base + (size_t)(qbase + (lane >> 2)) * H_ + wave * 32 + (lane & 3) * 8;
    const unsigned short* ksrc = Kg + base + (size_t)(kstart + (lane >> 2)) * H_ + wave * 32 + (lane & 3) * 8;
    #pragma unroll
    for (int p = 0; p < 4; p++) gld16(&Qs[wave][p * 16][0], qsrc + (size_t)p * 16 * H_);
    #pragma unroll
    for (int p = 0; p < 4; p++) gld16(&Ks[wave][p * 16][0], ksrc + (size_t)p * 16 * H_);

    // V tile -> registers (rows t0,t0+1 for two groups)
    const unsigned short* vsrc = Vg + base + (size_t)(kstart + wave * 8 + quad * 2) * H_ + l16 * 8;
    u16x8 vr[2][2];
    vr[0][0] = *(const u16x8*)vsrc;             vr[0][1] = *(const u16x8*)(vsrc + H_);
    vr[1][0] = *(const u16x8*)(vsrc + 32 * H_); vr[1][1] = *(const u16x8*)(vsrc + 33 * H_);

    f32x4 o[8];
    #pragma unroll
    for (int i = 0; i < 8; i++) o[i] = {0.f, 0.f, 0.f, 0.f};
    float m_i[4], l_i[4];
    #pragma unroll
    for (int r = 0; r < 4; r++) { m_i[r] = -INFINITY; l_i[r] = 0.f; }

    __syncthreads();   // Qs/Ks(0) staged (barrier drains vmcnt)

    // write Vt(0): packed pairs, XOR swizzle -> 2-way (free) bank pattern
    {
        #pragma unroll
        for (int g = 0; g < 2; g++) {
            int t0 = wave * 8 + g * 32 + quad * 2;
            int t8 = t0 >> 3;
            #pragma unroll
            for (int j = 0; j < 8; j++) {
                int h = l16 * 8 + j;
                unsigned pk = (unsigned)vr[g][0][j] | ((unsigned)vr[g][1][j] << 16);
                int blk = (t8 ^ (h & 7) ^ ((h >> 3) & 7)) & 7;
                *(unsigned*)&Vt[h * 64 + blk * 8 + (t0 & 7)] = pk;
            }
        }
    }

    bf16x8 qf[4];
    #pragma unroll
    for (int kk = 0; kk < 4; kk++) qf[kk] = *(bf16x8*)&Qs[kk][wave * 16 + l16][quad * 8];

    const int qloc = wave * 16 + quad * 4;

    for (int kt = 0; ; kt++) {
        const int kbase = kstart + kt * 64;
        // ---- S = Q K^T (16 rows x 64 cols per wave)
        f32x4 sf[4];
        #pragma unroll
        for (int nf = 0; nf < 4; nf++) sf[nf] = {0.f, 0.f, 0.f, 0.f};
        #pragma unroll
        for (int kk = 0; kk < 4; kk++)
            #pragma unroll
            for (int nf = 0; nf < 4; nf++) {
                bf16x8 bfr = *(bf16x8*)&Ks[kk][nf * 16 + l16][quad * 8];
                sf[nf] = MFMA16(qf[kk], bfr, sf[nf]);
            }
        // ---- causal mask (diagonal tile only; wave-uniform branch)
        if (kbase == qbase) {
            #pragma unroll
            for (int nf = 0; nf < 4; nf++) {
                int kloc = nf * 16 + l16;
                #pragma unroll
                for (int r = 0; r < 4; r++)
                    if (kloc > qloc + r) sf[nf][r] = -INFINITY;
            }
        }
        // ---- online softmax (rows owned per-wave; reduce over 16 lanes)
        float alpha[4];
        #pragma unroll
        for (int r = 0; r < 4; r++) {
            float v = fmaxf(fmaxf(sf[0][r], sf[1][r]), fmaxf(sf[2][r], sf[3][r]));
            v = fmaxf(v, __shfl_xor(v, 1, 64));
            v = fmaxf(v, __shfl_xor(v, 2, 64));
            v = fmaxf(v, __shfl_xor(v, 4, 64));
            v = fmaxf(v, __shfl_xor(v, 8, 64));
            float mnew = fmaxf(m_i[r], v);
            alpha[r] = __expf(m_i[r] - mnew);
            m_i[r] = mnew;
        }
        #pragma unroll
        for (int r = 0; r < 4; r++) {
            float rs = 0.f;
            #pragma unroll
            for (int nf = 0; nf < 4; nf++) {
                float e = __expf(sf[nf][r] - m_i[r]);
                sf[nf][r] = e; rs += e;
            }
            rs += __shfl_xor(rs, 1, 64);
            rs += __shfl_xor(rs, 2, 64);
            rs += __shfl_xor(rs, 4, 64);
            rs += __shfl_xor(rs, 8, 64);
            l_i[r] = alpha[r] * l_i[r] + rs;
        }
        #pragma unroll
        for (int nf = 0; nf < 4; nf++)
            #pragma unroll
            for (int r = 0; r < 4; r++)
                Ps[wave][quad * 4 + r][nf * 16 + l16] = f2bf(sf[nf][r]);
        #pragma unroll
        for (int i = 0; i < 8; i++) {
            o[i][0] *= alpha[0]; o[i][1] *= alpha[1];
            o[i][2] *= alpha[2]; o[i][3] *= alpha[3];
        }
        __syncthreads();   // B: Vt visible to all; Ks reads done -> restage OK

        const bool more = (kt + 1 < niter);
        if (more) {        // async prefetch next K tile; V tile -> regs
            ksrc += 64 * H_;
            #pragma unroll
            for (int p = 0; p < 4; p++) gld16(&Ks[wave][p * 16][0], ksrc + (size_t)p * 16 * H_);
            vsrc += 64 * H_;
            vr[0][0] = *(const u16x8*)vsrc;             vr[0][1] = *(const u16x8*)(vsrc + H_);
            vr[1][0] = *(const u16x8*)(vsrc + 32 * H_); vr[1][1] = *(const u16x8*)(vsrc + 33 * H_);
        }
        // ---- O += P V   (overlaps the in-flight prefetch)
        bf16x8 pa0 = *(bf16x8*)&Ps[wave][l16][quad * 8];
        bf16x8 pa1 = *(bf16x8*)&Ps[wave][l16][32 + quad * 8];
        #pragma unroll
        for (int nf = 0; nf < 8; nf++) {
            int h = nf * 16 + l16;
            int ex = (h & 7) ^ ((h >> 3) & 7);
            bf16x8 v0 = *(bf16x8*)&Vt[h * 64 + ((quad ^ ex) & 7) * 8];
            bf16x8 v1 = *(bf16x8*)&Vt[h * 64 + (((quad + 4) ^ ex) & 7) * 8];
            o[nf] = MFMA16(pa0, v0, o[nf]);
            o[nf] = MFMA16(pa1, v1, o[nf]);
        }
        if (!more) break;
        __syncthreads();   // A: next Ks landed; Vt free to overwrite
        #pragma unroll
        for (int g = 0; g < 2; g++) {
            int t0 = wave * 8 + g * 32 + quad * 2;
            int t8 = t0 >> 3;
            #pragma unroll
            for (int j = 0; j < 8; j++) {
                int h = l16 * 8 + j;
                unsigned pk = (unsigned)vr[g][0][j] | ((unsigned)vr[g][1][j] << 16);
                int blk = (t8 ^ (h & 7) ^ ((h >> 3) & 7)) & 7;
                *(unsigned*)&Vt[h * 64 + blk * 8 + (t0 & 7)] = pk;
            }
        }
    }

    // ---- partial epilogue: normalized O (bf16) + (m,l) per row
    const size_t obase = ((size_t)((qt * 8 + b) * 4 + s)) * 64 * 128;
    #pragma unroll
    for (int r = 0; r < 4; r++) {
        float invl = 1.0f / l_i[r];
        #pragma unroll
        for (int nf = 0; nf < 8; nf++)
            Ob[obase + (size_t)(qloc + r) * 128 + nf * 16 + l16] = f2bf(o[nf][r] * invl);
    }
    if (l16 == 0) {
        int ridx = ((qt * 8 + b) * 4 + s) * 64 + qloc;
        #pragma unroll
        for (int r = 0; r < 4; r++) { Ml[(ridx + r) * 2] = m_i[r]; Ml[(ridx + r) * 2 + 1] = l_i[r]; }
    }
}

// ---------- kernel 4: merge splits (log-sum-exp recombination) ----------
__global__ __launch_bounds__(256) void merge(const unsigned short* __restrict__ Ob,
                                             const float* __restrict__ Ml,
                                             float* __restrict__ out) {
    const int qt = blockIdx.x, b = blockIdx.y;
    const int ns = (qt >> 3) + 1;
    const int tid = threadIdx.x;
    const int row = tid >> 2, c0 = (tid & 3) * 32;
    const int pb = (qt * 8 + b) * 4;

    float mv[4], lv[4], mg = -INFINITY;
    for (int s2 = 0; s2 < ns; s2++) {
        mv[s2] = Ml[((pb + s2) * 64 + row) * 2];
        lv[s2] = Ml[((pb + s2) * 64 + row) * 2 + 1];
        mg = fmaxf(mg, mv[s2]);
    }
    float L = 0.f, w[4];
    for (int s2 = 0; s2 < ns; s2++) { w[s2] = lv[s2] * __expf(mv[s2] - mg); L += w[s2]; }
    float inv = 1.0f / L;

    float accv[32];
    #pragma unroll
    for (int i = 0; i < 32; i++) accv[i] = 0.f;
    for (int s2 = 0; s2 < ns; s2++) {
        const unsigned short* op = Ob + ((size_t)((pb + s2) * 64 + row)) * 128 + c0;
        #pragma unroll
        for (int cc = 0; cc < 4; cc++) {
            u16x8 v = *(const u16x8*)(op + cc * 8);
            #pragma unroll
            for (int j = 0; j < 8; j++) accv[cc * 8 + j] += w[s2] * bf2f(v[j]);
        }
    }
    float* od = out + ((size_t)(b * T_ + qt * 64 + row)) * 128 + c0;
    #pragma unroll
    for (int cc = 0; cc < 8; cc++) {
        float4 w4 = { accv[cc*4] * inv, accv[cc*4+1] * inv, accv[cc*4+2] * inv, accv[cc*4+3] * inv };
        *(float4*)(od + cc * 4) = w4;
    }
}

extern "C" void kernel_launch(void* const* d_in, const int* in_sizes, int n_in,
                              void* d_out, int out_size, void* d_ws, size_t ws_size,
                              hipStream_t stream) {
    const float* x  = (const float*)d_in[0];
    const float* Wq = (const float*)d_in[1];
    const float* Wk = (const float*)d_in[2];
    const float* Wv = (const float*)d_in[3];

    char* ws = (char*)d_ws;
    unsigned short* Wb = (unsigned short*)ws;                         // 0.75 MB @ 0
    unsigned short* xb = (unsigned short*)(ws + (size_t)(1u << 20));  // 32 MB @ 1 MB
    unsigned short* Ob = (unsigned short*)(ws + (size_t)(1u << 20));  // 16 MB, aliases xb (used after proj)
    float*          Ml = (float*)(ws + (size_t)18 * (1u << 20));      // 0.5 MB @ 18 MB (inside xb region)
    unsigned short* Q  = (unsigned short*)(ws + (size_t)34 * (1u << 20));
    unsigned short* K  = Q + (size_t)16384 * 128;
    unsigned short* V  = K + (size_t)16384 * 128;
    float* out = (float*)d_out;

    hipLaunchKernelGGL(xwconv, dim3(8384), dim3(256), 0, stream, x, Wq, Wk, Wv, xb, Wb);
    hipLaunchKernelGGL(proj,   dim3(128, 3), dim3(256), 0, stream, xb, Wb, Q, K, V);
    hipLaunchKernelGGL(attn,   dim3(32, NB, 4), dim3(256), 0, stream, Q, K, V, Ob, Ml);
    hipLaunchKernelGGL(merge,  dim3(32, NB), dim3(256), 0, stream, Ob, Ml, out);
}

// Round 3
// 173.848 us; speedup vs baseline: 1.8896x; 1.0508x over previous
//
#include <hip/hip_runtime.h>
#include <hip/hip_bf16.h>
#include <math.h>

#define T_ 2048
#define C_ 1024
#define H_ 128
#define NB 8
#define WN 131072                 // 128*1024 per weight
#define SC 0.08838834764831845f   // 1/sqrt(128)

typedef __attribute__((ext_vector_type(8))) short bf16x8;
typedef __attribute__((ext_vector_type(8))) unsigned short u16x8;
typedef __attribute__((ext_vector_type(4))) float f32x4;

#define MFMA16(a,b,c) __builtin_amdgcn_mfma_f32_16x16x32_bf16((a),(b),(c),0,0,0)

__device__ __forceinline__ unsigned short f2bf(float f) {
    union { float f; unsigned u; } v; v.f = f;
    unsigned r = v.u + 0x7fffu + ((v.u >> 16) & 1u);
    return (unsigned short)(r >> 16);
}
__device__ __forceinline__ float bf2f(unsigned short u) {
    union { unsigned u; float f; } v; v.u = ((unsigned)u) << 16; return v.f;
}
__device__ __forceinline__ unsigned pk2bf(float a, float b) {
    __hip_bfloat162 h = __float22bfloat162_rn(float2{a, b});
    union { __hip_bfloat162 h; unsigned u; } v; v.h = h; return v.u;
}
// async global->LDS, 16B per lane; lds dest = uniform base + laneid*16
__device__ __forceinline__ void gld16(void* lds, const void* g) {
    __builtin_amdgcn_global_load_lds(
        (const __attribute__((address_space(1))) unsigned*)g,
        (__attribute__((address_space(3))) unsigned*)lds, 16, 0, 0);
}

// ---------- kernel 1: W fp32 -> bf16 (Wq pre-scaled by 1/sqrt(H)) ----------
__global__ __launch_bounds__(256) void wconv(const float* __restrict__ Wq,
                                             const float* __restrict__ Wk,
                                             const float* __restrict__ Wv,
                                             unsigned short* __restrict__ Wb) {
    int e = (blockIdx.x * 256 + threadIdx.x) * 8;       // < 393216
    int which = e >> 17;
    int off = e & (WN - 1);
    const float* src = (which == 0) ? Wq : (which == 1 ? Wk : Wv);
    float s = (which == 0) ? SC : 1.0f;
    const float4* p = (const float4*)(src + off);
    float4 a = p[0], b = p[1];
    uint4 o = { pk2bf(a.x * s, a.y * s), pk2bf(a.z * s, a.w * s),
                pk2bf(b.x * s, b.y * s), pk2bf(b.z * s, b.w * s) };
    *(uint4*)(Wb + e) = o;
}

// ---------- kernel 2: fused QKV projection ----------
// grid 256 (1 block/CU): m-tile 64, n = 384 (q|k|v), BK=64, dbuf single-barrier.
__global__ __launch_bounds__(256, 1) void proj(const float* __restrict__ x,
                                               const unsigned short* __restrict__ Wb,
                                               unsigned short* __restrict__ Q,
                                               unsigned short* __restrict__ K,
                                               unsigned short* __restrict__ V) {
    __shared__ unsigned short Xs[2][2][64][40];    // 20 KB (pad 40: conflict-free reads)
    __shared__ unsigned short Ws[2][2][384][32];   // 96 KB

    const int tid  = threadIdx.x;
    const int wave = tid >> 6, lane = tid & 63;
    const int quad = lane >> 4, l16 = lane & 15;
    const int m0   = blockIdx.x * 64;

    f32x4 acc[4][6];
    #pragma unroll
    for (int i = 0; i < 4; i++)
        #pragma unroll
        for (int j = 0; j < 6; j++) acc[i][j] = {0.f, 0.f, 0.f, 0.f};

    const int xrow = tid >> 2, xcg = tid & 3;
    const int xck = xcg >> 1, xco = (xcg & 1) * 16;
    const float* xg = x + (size_t)(m0 + xrow) * C_ + xcg * 16;
    const unsigned short* wg = Wb + (size_t)(wave * 96 + (lane >> 2)) * C_ + (lane & 3) * 8;

    #define STAGE(buf, kc) do {                                                   \
        _Pragma("unroll")                                                         \
        for (int kkc = 0; kkc < 2; kkc++)                                         \
            _Pragma("unroll")                                                     \
            for (int rb = 0; rb < 6; rb++)                                        \
                gld16(&Ws[buf][kkc][wave * 96 + rb * 16][0],                      \
                      wg + (size_t)rb * 16 * C_ + (kc) + kkc * 32);               \
        const float* xp = xg + (kc);                                              \
        float4 f0 = *(const float4*)xp,      f1 = *(const float4*)(xp + 4);       \
        float4 f2 = *(const float4*)(xp + 8), f3 = *(const float4*)(xp + 12);     \
        uint4 u0 = { pk2bf(f0.x,f0.y), pk2bf(f0.z,f0.w),                          \
                     pk2bf(f1.x,f1.y), pk2bf(f1.z,f1.w) };                        \
        uint4 u1 = { pk2bf(f2.x,f2.y), pk2bf(f2.z,f2.w),                          \
                     pk2bf(f3.x,f3.y), pk2bf(f3.z,f3.w) };                        \
        *(uint4*)&Xs[buf][xck][xrow][xco]     = u0;                               \
        *(uint4*)&Xs[buf][xck][xrow][xco + 8] = u1;                               \
    } while (0)

    STAGE(0, 0);
    for (int it = 0; it < 16; it++) {
        __syncthreads();                       // buf[it&1] ready (staged 1 iter ago)
        if (it < 15) { STAGE((it + 1) & 1, (it + 1) * 64); }
        const int buf = it & 1;
        bf16x8 af[4][2];
        #pragma unroll
        for (int kk = 0; kk < 2; kk++)
            #pragma unroll
            for (int mf = 0; mf < 4; mf++)
                af[mf][kk] = *(bf16x8*)&Xs[buf][kk][mf * 16 + l16][quad * 8];
        #pragma unroll
        for (int kk = 0; kk < 2; kk++)
            #pragma unroll
            for (int nf = 0; nf < 6; nf++) {
                bf16x8 bq = *(bf16x8*)&Ws[buf][kk][wave * 96 + nf * 16 + l16][quad * 8];
                #pragma unroll
                for (int mf = 0; mf < 4; mf++)
                    acc[mf][nf] = MFMA16(af[mf][kk], bq, acc[mf][nf]);
            }
    }
    #undef STAGE

    #pragma unroll
    for (int nf = 0; nf < 6; nf++) {
        int nb = wave * 96 + nf * 16;
        int which = nb >> 7;                   // frag-uniform
        unsigned short* dst = (which == 0) ? Q : (which == 1 ? K : V);
        int c = (nb & 127) + l16;
        #pragma unroll
        for (int mf = 0; mf < 4; mf++)
            #pragma unroll
            for (int r = 0; r < 4; r++)
                dst[(size_t)(m0 + mf * 16 + quad * 4 + r) * H_ + c] = f2bf(acc[mf][nf][r]);
    }
}

// ---------- kernel 3: split-K flash causal attention (S^T layout) ----------
// grid (256, 8): bx -> {s = bx&7, qt = 31-(bx>>3)}, y = batch. K-tile 64, split 256.
__global__ __launch_bounds__(256, 3) void attn(const unsigned short* __restrict__ Qg,
                                               const unsigned short* __restrict__ Kg,
                                               const unsigned short* __restrict__ Vg,
                                               unsigned short* __restrict__ Ob,
                                               float* __restrict__ Ml) {
    const int bx = blockIdx.x;
    const int s  = bx & 7, qt = 31 - (bx >> 3);
    const int b  = blockIdx.y;
    const int qbase = qt * 64, kstart = s * 256;
    if (kstart > qbase) return;                               // inactive split
    const int kend  = (kstart + 256 < qbase + 64) ? kstart + 256 : qbase + 64;
    const int niter = (kend - kstart) >> 6;

    __shared__ unsigned short Ks[4][64][32];   // 16 KB (chunked by H/32)
    __shared__ unsigned short Vt[128 * 64];    // 16 KB (packed-pair XOR-swizzled transpose)
    __shared__ unsigned short Ps[4][16][64];   //  8 KB (per-wave P^T->A, XOR-swizzled)

    const int tid = threadIdx.x, wave = tid >> 6, lane = tid & 63;
    const int quad = lane >> 4, l16 = lane & 15;
    const size_t base = (size_t)b * T_ * H_;

    // K staging (async) + V regs
    const unsigned short* ksrc = Kg + base + (size_t)(kstart + (lane >> 2)) * H_ + wave * 32 + (lane & 3) * 8;
    #pragma unroll
    for (int p = 0; p < 4; p++) gld16(&Ks[wave][p * 16][0], ksrc + (size_t)p * 16 * H_);
    const unsigned short* vsrc = Vg + base + (size_t)(kstart + wave * 8 + quad * 2) * H_ + l16 * 8;
    u16x8 vr[2][2];
    vr[0][0] = *(const u16x8*)vsrc;             vr[0][1] = *(const u16x8*)(vsrc + H_);
    vr[1][0] = *(const u16x8*)(vsrc + 32 * H_); vr[1][1] = *(const u16x8*)(vsrc + 33 * H_);

    // Q fragments straight from global (loop-invariant)
    bf16x8 qf[4];
    const unsigned short* qp = Qg + base + (size_t)(qbase + wave * 16 + l16) * H_ + quad * 8;
    #pragma unroll
    for (int kk = 0; kk < 4; kk++) qf[kk] = *(const bf16x8*)(qp + kk * 32);

    f32x4 o[8];
    #pragma unroll
    for (int i = 0; i < 8; i++) o[i] = {0.f, 0.f, 0.f, 0.f};
    float m_i = -INFINITY, l_i = 0.f;
    const int swz = (l16 & 7) << 3;
    const int qg = qbase + wave * 16 + l16;    // this lane's q-row

    __syncthreads();                           // Ks(0) landed (barrier drains vmcnt)

    // write Vt(0): packed pairs, XOR swizzle (2-way = free)
    #pragma unroll
    for (int g = 0; g < 2; g++) {
        int t0 = wave * 8 + g * 32 + quad * 2;
        int t8 = t0 >> 3;
        #pragma unroll
        for (int j = 0; j < 8; j++) {
            int h = l16 * 8 + j;
            unsigned pk = (unsigned)(unsigned short)vr[g][0][j] | ((unsigned)(unsigned short)vr[g][1][j] << 16);
            int blk = (t8 ^ (h & 7) ^ ((h >> 3) & 7)) & 7;
            *(unsigned*)&Vt[h * 64 + blk * 8 + (t0 & 7)] = pk;
        }
    }

    for (int kt = 0; ; kt++) {
        const int kbase = kstart + kt * 64;
        // ---- S^T = K Q^T : rows k (quad*4+r within nf*16), col q = l16
        f32x4 st[4];
        #pragma unroll
        for (int nf = 0; nf < 4; nf++) st[nf] = {0.f, 0.f, 0.f, 0.f};
        #pragma unroll
        for (int kk = 0; kk < 4; kk++)
            #pragma unroll
            for (int nf = 0; nf < 4; nf++) {
                bf16x8 kfr = *(bf16x8*)&Ks[kk][nf * 16 + l16][quad * 8];
                st[nf] = MFMA16(kfr, qf[kk], st[nf]);
            }
        // ---- causal mask (diagonal region only; block-uniform branch)
        if (kbase + 64 > qbase) {
            #pragma unroll
            for (int nf = 0; nf < 4; nf++) {
                int kg = kbase + nf * 16 + quad * 4;
                #pragma unroll
                for (int r = 0; r < 4; r++)
                    if (kg + r > qg) st[nf][r] = -INFINITY;
            }
        }
        // ---- online softmax: per-lane q, 15 reg-max + 2 shuffles
        float mx = st[0][0];
        #pragma unroll
        for (int nf = 0; nf < 4; nf++)
            #pragma unroll
            for (int r = 0; r < 4; r++) mx = fmaxf(mx, st[nf][r]);
        mx = fmaxf(mx, __shfl_xor(mx, 16, 64));
        mx = fmaxf(mx, __shfl_xor(mx, 32, 64));
        float mnew = fmaxf(m_i, mx);
        float al = __expf(m_i - mnew);
        m_i = mnew;
        float rs = 0.f;
        #pragma unroll
        for (int nf = 0; nf < 4; nf++)
            #pragma unroll
            for (int r = 0; r < 4; r++) {
                float e = __expf(st[nf][r] - mnew);
                st[nf][r] = e; rs += e;
            }
        rs += __shfl_xor(rs, 16, 64);
        rs += __shfl_xor(rs, 32, 64);
        l_i = al * l_i + rs;
        // ---- P^T -> Ps (A-layout source), packed b64 writes, swizzled
        #pragma unroll
        for (int nf = 0; nf < 4; nf++) {
            uint2 pk = { pk2bf(st[nf][0], st[nf][1]), pk2bf(st[nf][2], st[nf][3]) };
            *(uint2*)&Ps[wave][l16][(nf * 16 + quad * 4) ^ swz] = pk;
        }
        // ---- rescale O (alpha lives at lane l16=q; O rows are quad*4+r)
        float a0 = __shfl(al, quad * 4 + 0, 64), a1 = __shfl(al, quad * 4 + 1, 64);
        float a2 = __shfl(al, quad * 4 + 2, 64), a3 = __shfl(al, quad * 4 + 3, 64);
        #pragma unroll
        for (int i = 0; i < 8; i++) {
            o[i][0] *= a0; o[i][1] *= a1; o[i][2] *= a2; o[i][3] *= a3;
        }
        __syncthreads();   // B: Vt complete, all Ks reads done

        const bool more = (kt + 1 < niter);
        if (more) {        // async prefetch next K; V tile -> regs
            ksrc += 64 * H_;
            #pragma unroll
            for (int p = 0; p < 4; p++) gld16(&Ks[wave][p * 16][0], ksrc + (size_t)p * 16 * H_);
            vsrc += 64 * H_;
            vr[0][0] = *(const u16x8*)vsrc;             vr[0][1] = *(const u16x8*)(vsrc + H_);
            vr[1][0] = *(const u16x8*)(vsrc + 32 * H_); vr[1][1] = *(const u16x8*)(vsrc + 33 * H_);
        }
        // ---- O += P V (overlaps in-flight prefetch)
        bf16x8 pa0 = *(bf16x8*)&Ps[wave][l16][(quad * 8) ^ swz];
        bf16x8 pa1 = *(bf16x8*)&Ps[wave][l16][(32 + quad * 8) ^ swz];
        #pragma unroll
        for (int nf = 0; nf < 8; nf++) {
            int h = nf * 16 + l16;
            int ex = (h & 7) ^ ((h >> 3) & 7);
            bf16x8 v0 = *(bf16x8*)&Vt[h * 64 + ((quad ^ ex) & 7) * 8];
            bf16x8 v1 = *(bf16x8*)&Vt[h * 64 + (((quad + 4) ^ ex) & 7) * 8];
            o[nf] = MFMA16(pa0, v0, o[nf]);
            o[nf] = MFMA16(pa1, v1, o[nf]);
        }
        if (!more) break;
        __syncthreads();   // A: next Ks landed; Vt free to overwrite
        #pragma unroll
        for (int g = 0; g < 2; g++) {
            int t0 = wave * 8 + g * 32 + quad * 2;
            int t8 = t0 >> 3;
            #pragma unroll
            for (int j = 0; j < 8; j++) {
                int h = l16 * 8 + j;
                unsigned pk = (unsigned)(unsigned short)vr[g][0][j] | ((unsigned)(unsigned short)vr[g][1][j] << 16);
                int blk = (t8 ^ (h & 7) ^ ((h >> 3) & 7)) & 7;
                *(unsigned*)&Vt[h * 64 + blk * 8 + (t0 & 7)] = pk;
            }
        }
    }

    // ---- partial epilogue: normalized O (bf16) + (m,l) per row
    const int g2 = qt >> 2;
    const int Pq = 2 * g2 * (g2 + 1) + (qt & 3) * (g2 + 1);   // prefix of split counts
    const int slot = (Pq + s) * NB + b;
    float lq[4];
    #pragma unroll
    for (int r = 0; r < 4; r++) lq[r] = __shfl(l_i, quad * 4 + r, 64);
    const size_t obase = (size_t)slot * 64 * 128;
    #pragma unroll
    for (int r = 0; r < 4; r++) {
        float invl = 1.0f / lq[r];
        #pragma unroll
        for (int nf = 0; nf < 8; nf++)
            Ob[obase + (size_t)(wave * 16 + quad * 4 + r) * 128 + nf * 16 + l16] = f2bf(o[nf][r] * invl);
    }
    if (lane < 16) {
        int ridx = slot * 64 + wave * 16 + l16;
        Ml[ridx * 2]     = m_i;
        Ml[ridx * 2 + 1] = l_i;
    }
}

// ---------- kernel 4: merge splits (log-sum-exp recombination) ----------
__global__ __launch_bounds__(256) void merge(const unsigned short* __restrict__ Ob,
                                             const float* __restrict__ Ml,
                                             float* __restrict__ out) {
    const int qt = blockIdx.x, b = blockIdx.y;
    const int g = qt >> 2;
    const int Pq = 2 * g * (g + 1) + (qt & 3) * (g + 1);
    const int ns = g + 1;
    const int tid = threadIdx.x;
    const int row = tid >> 2, c0 = (tid & 3) * 32;

    float mv[8], lv[8], mg = -INFINITY;
    for (int s2 = 0; s2 < ns; s2++) {
        int slot = (Pq + s2) * NB + b;
        mv[s2] = Ml[(slot * 64 + row) * 2];
        lv[s2] = Ml[(slot * 64 + row) * 2 + 1];
        mg = fmaxf(mg, mv[s2]);
    }
    float L = 0.f, w[8];
    for (int s2 = 0; s2 < ns; s2++) { w[s2] = lv[s2] * __expf(mv[s2] - mg); L += w[s2]; }
    float inv = 1.0f / L;

    float accv[32];
    #pragma unroll
    for (int i = 0; i < 32; i++) accv[i] = 0.f;
    for (int s2 = 0; s2 < ns; s2++) {
        int slot = (Pq + s2) * NB + b;
        const unsigned short* op = Ob + ((size_t)(slot * 64 + row)) * 128 + c0;
        #pragma unroll
        for (int cc = 0; cc < 4; cc++) {
            u16x8 v = *(const u16x8*)(op + cc * 8);
            #pragma unroll
            for (int j = 0; j < 8; j++) accv[cc * 8 + j] += w[s2] * bf2f(v[j]);
        }
    }
    float* od = out + ((size_t)(b * T_ + qt * 64 + row)) * 128 + c0;
    #pragma unroll
    for (int cc = 0; cc < 8; cc++) {
        float4 w4 = { accv[cc*4] * inv, accv[cc*4+1] * inv, accv[cc*4+2] * inv, accv[cc*4+3] * inv };
        *(float4*)(od + cc * 4) = w4;
    }
}

extern "C" void kernel_launch(void* const* d_in, const int* in_sizes, int n_in,
                              void* d_out, int out_size, void* d_ws, size_t ws_size,
                              hipStream_t stream) {
    const float* x  = (const float*)d_in[0];
    const float* Wq = (const float*)d_in[1];
    const float* Wk = (const float*)d_in[2];
    const float* Wv = (const float*)d_in[3];

    char* ws = (char*)d_ws;
    unsigned short* Wb = (unsigned short*)ws;                          // 0.75 MB @ 0
    unsigned short* Q  = (unsigned short*)(ws + (size_t) 1 * (1u << 20)); // 4 MB
    unsigned short* K  = (unsigned short*)(ws + (size_t) 5 * (1u << 20));
    unsigned short* V  = (unsigned short*)(ws + (size_t) 9 * (1u << 20));
    unsigned short* Ob = (unsigned short*)(ws + (size_t)13 * (1u << 20)); // 18.9 MB (1152 slots)
    float*          Ml = (float*)(ws + (size_t)32 * (1u << 20));          // 0.6 MB
    float* out = (float*)d_out;

    hipLaunchKernelGGL(wconv, dim3(192), dim3(256), 0, stream, Wq, Wk, Wv, Wb);
    hipLaunchKernelGGL(proj,  dim3(256), dim3(256), 0, stream, x, Wb, Q, K, V);
    hipLaunchKernelGGL(attn,  dim3(256, NB), dim3(256), 0, stream, Q, K, V, Ob, Ml);
    hipLaunchKernelGGL(merge, dim3(32, NB), dim3(256), 0, stream, Ob, Ml, out);
}